// Round 12
// baseline (3073.224 us; speedup 1.0000x reference)
//
#include <hip/hip_runtime.h>

constexpr int D = 300;
constexpr int KP = 320;   // K padded to multiple of 32

static inline int cdiv(int a, int b){ return (a + b - 1) / b; }

__device__ __forceinline__ unsigned short f2bf(float f){
  unsigned u = __float_as_uint(f);
  unsigned r = (u + 0x7fffu + ((u >> 16) & 1u)) >> 16;
  return (unsigned short)r;
}
__device__ __forceinline__ float bf2f(unsigned short h){
  return __uint_as_float((unsigned)h << 16);
}
__device__ __forceinline__ float pread(const unsigned short* __restrict__ h,
                                       const unsigned short* __restrict__ l, size_t i){
  return bf2f(h[i]) + bf2f(l[i]);
}
__device__ __forceinline__ void pwrite(unsigned short* __restrict__ h,
                                       unsigned short* __restrict__ l, size_t i, float v){
  unsigned short hi = f2bf(v);
  h[i] = hi; l[i] = f2bf(v - bf2f(hi));
}
// bijective XCD-chunk swizzle (m204): hardware bid -> chunked work id
__device__ __forceinline__ int xcd_chunk(int bid, int nwg){
  int q = nwg >> 3, r = nwg & 7;
  int x = bid & 7, i = bid >> 3;
  return (x < r ? x * (q + 1) : r * (q + 1) + (x - r) * q) + i;
}

typedef __attribute__((ext_vector_type(8))) short bf16x8;
typedef __attribute__((ext_vector_type(4))) float f32x4;
typedef unsigned short us;

// ------- fp32 [M x 300] (row stride ld) -> hi/lo bf16 planes [Mpad x 320] ---
__global__ void k_cvt2(const float* __restrict__ src, int ld, int M,
                       us* __restrict__ hb, us* __restrict__ lb, int total){
  int idx = blockIdx.x * blockDim.x + threadIdx.x;
  if (idx >= total) return;
  int r = idx / 80, k4 = (idx - r * 80) * 4;
  const float* row = src + (size_t)r * ld;
  bool rm = r < M;
  ushort4 oh, ol;
  float x;
  x = (rm && k4 + 0 < D) ? row[k4 + 0] : 0.f; oh.x = f2bf(x); ol.x = f2bf(x - bf2f(oh.x));
  x = (rm && k4 + 1 < D) ? row[k4 + 1] : 0.f; oh.y = f2bf(x); ol.y = f2bf(x - bf2f(oh.y));
  x = (rm && k4 + 2 < D) ? row[k4 + 2] : 0.f; oh.z = f2bf(x); ol.z = f2bf(x - bf2f(oh.z));
  x = (rm && k4 + 3 < D) ? row[k4 + 3] : 0.f; oh.w = f2bf(x); ol.w = f2bf(x - bf2f(oh.w));
  *(ushort4*)(hb + (size_t)r * KP + k4) = oh;
  *(ushort4*)(lb + (size_t)r * KP + k4) = ol;
}

// ------- GRU weight pack: [jt(10)][ks(10)][t(12)][kg(4)][row(32)][8 halves] --
__global__ void k_wpack(const float* __restrict__ Wih, const float* __restrict__ Whh,
                        us* __restrict__ out){
  int idx = blockIdx.x * blockDim.x + threadIdx.x;
  if (idx >= 307200) return;
  int h4 = idx * 4;
  int jtks = h4 / 12288;
  int within = h4 - jtks * 12288;
  int jt = jtks / 10, ks = jtks - (jtks / 10) * 10;
  int t = within >> 10;
  int w2 = within & 1023;
  int kg = w2 >> 8;
  int row = (w2 >> 3) & 31;
  int h0 = w2 & 7;
  int m = t / 6, g = (t >> 1) % 3, p = t & 1;
  int j = jt * 32 + row;
  const float* W = m ? Whh : Wih;
  ushort4 o;
  us* po = (us*)&o;
  #pragma unroll
  for (int u = 0; u < 4; ++u){
    int k = ks * 32 + kg * 8 + h0 + u;
    float v = (j < D && k < D) ? W[(size_t)(g * D + j) * D + k] : 0.f;
    us hi = f2bf(v);
    po[u] = p ? f2bf(v - bf2f(hi)) : hi;
  }
  *(ushort4*)(out + h4) = o;
}

// ------- bf16x3 MFMA gemm (single-buffer LDS) ------------------------------
template<int MODE>
__global__ void k_mfma3(const us* __restrict__ Ah, const us* __restrict__ Al,
                        const us* __restrict__ Bh, const us* __restrict__ Bl,
                        const float* __restrict__ bias,
                        us* __restrict__ Ch, us* __restrict__ Cl,
                        int M, int NC){
  __shared__ short ls[4][4096];   // Ah,Al,Bh,Bl tiles: [kg(4)][row(128)][8]
  const int tid = threadIdx.x;
  const int lane = tid & 63;
  const int wid = tid >> 6, wr = wid >> 1, wc = wid & 1;
  int work = xcd_chunk(blockIdx.x, gridDim.x);
  const int rowBase = (work / 3) * 128, colBase = (work - (work / 3) * 3) * 128;
  const int l15 = lane & 15, l4 = lane >> 4;
  f32x4 acc[4][4] = {};
  const us* gsrc[4] = {Ah, Al, Bh, Bl};

  for (int k0 = 0; k0 < KP; k0 += 32){
    #pragma unroll
    for (int t = 0; t < 4; ++t){
      int base = (t < 2) ? rowBase : colBase;
      #pragma unroll
      for (int s = 0; s < 2; ++s){
        int lin = s * 256 + tid;
        int kg = lin >> 7, row = lin & 127;
        const us* g = gsrc[t] + (size_t)(base + row) * KP + k0 + kg * 8;
        short* lb = &ls[t][0] + (size_t)(s * 256 + (tid & ~63)) * 8;
        __builtin_amdgcn_global_load_lds((const __attribute__((address_space(1))) unsigned*)g,
                                         (__attribute__((address_space(3))) unsigned*)lb, 16, 0, 0);
      }
    }
    __syncthreads();
    bf16x8 fbh[4], fbl[4];
    #pragma unroll
    for (int j = 0; j < 4; ++j){
      int bi = l4 * 128 + wc * 64 + j * 16 + l15;
      fbh[j] = *(const bf16x8*)(&ls[2][0] + (size_t)bi * 8);
      fbl[j] = *(const bf16x8*)(&ls[3][0] + (size_t)bi * 8);
    }
    #pragma unroll
    for (int i = 0; i < 4; ++i){
      int ai = l4 * 128 + wr * 64 + i * 16 + l15;
      bf16x8 fah = *(const bf16x8*)(&ls[0][0] + (size_t)ai * 8);
      bf16x8 fal = *(const bf16x8*)(&ls[1][0] + (size_t)ai * 8);
      #pragma unroll
      for (int j = 0; j < 4; ++j){
        acc[i][j] = __builtin_amdgcn_mfma_f32_16x16x32_bf16(fah, fbh[j], acc[i][j], 0, 0, 0);
        acc[i][j] = __builtin_amdgcn_mfma_f32_16x16x32_bf16(fah, fbl[j], acc[i][j], 0, 0, 0);
        acc[i][j] = __builtin_amdgcn_mfma_f32_16x16x32_bf16(fal, fbh[j], acc[i][j], 0, 0, 0);
      }
    }
    __syncthreads();
  }

  #pragma unroll
  for (int i = 0; i < 4; ++i){
    #pragma unroll
    for (int q = 0; q < 4; ++q){
      int r = rowBase + wr * 64 + i * 16 + l4 * 4 + q;
      if (r >= M) continue;
      #pragma unroll
      for (int j = 0; j < 4; ++j){
        int c = colBase + wc * 64 + j * 16 + l15;
        if (c >= KP) continue;
        size_t o = (size_t)r * KP + c;
        if (c >= NC){ Ch[o] = 0; Cl[o] = 0; continue; }
        float v = acc[i][j][q];
        if (MODE) v += bias[c];
        if (MODE == 1) v = v > 0.f ? v : 0.01f * v;
        if (MODE == 2) v = v > 0.f ? v : (expf(v) - 1.f);
        pwrite(Ch, Cl, o, v);
      }
    }
  }
}

// ---------------- GRU v7: depth-3 pipeline, counted vmcnt, raw barriers ----
__global__ __launch_bounds__(256, 2) void k_gru(
    const us* __restrict__ Ih, const us* __restrict__ Il,
    const us* __restrict__ Hh, const us* __restrict__ Hl,
    const us* __restrict__ Wp,
    const float* __restrict__ bih, const float* __restrict__ bhh,
    us* __restrict__ Oh, us* __restrict__ Ol){
  __shared__ short lsW[3][12288];   // 3 x 24 KB = 72 KB
  const int tid = threadIdx.x, lane = tid & 63, wid = tid >> 6;
  const int l15 = lane & 15, l4 = lane >> 4;
  int work = xcd_chunk(blockIdx.x, gridDim.x);
  const int rt = work / 10, jt = work - rt * 10;
  const int rowBase = rt * 128;
  f32x4 acc[2][2][6] = {};
  const us* asrc[4] = {Ih, Il, Hh, Hl};
  bf16x8 fa[3][2][4];   // [buf][r][tensor]

  auto loadA = [&](int ks, int buf){
    int k0 = ks * 32;
    #pragma unroll
    for (int r = 0; r < 2; ++r){
      size_t base = (size_t)(rowBase + wid * 32 + r * 16 + l15) * KP + k0 + l4 * 8;
      #pragma unroll
      for (int t = 0; t < 4; ++t)
        fa[buf][r][t] = *(const bf16x8*)(asrc[t] + base);
    }
  };
  auto stageW = [&](int ks, int buf){
    const us* wsrc = Wp + (size_t)(jt * 10 + ks) * 12288;
    #pragma unroll
    for (int s = 0; s < 6; ++s){
      int lin = s * 256 + tid;
      __builtin_amdgcn_global_load_lds(
        (const __attribute__((address_space(1))) unsigned*)(wsrc + (size_t)lin * 8),
        (__attribute__((address_space(3))) unsigned*)(&lsW[buf][0] + (size_t)(s * 256 + (tid & ~63)) * 8),
        16, 0, 0);
    }
  };
  auto compute = [&](int buf){
    #pragma unroll
    for (int c = 0; c < 2; ++c){
      #pragma unroll
      for (int mg = 0; mg < 6; ++mg){
        const int m = mg / 3, g = mg % 3, tH = m * 6 + g * 2;
        int wro = c * 16 + l15;
        bf16x8 wh = *(const bf16x8*)(&lsW[buf][0] + (size_t)((tH * 4 + l4) * 32 + wro) * 8);
        bf16x8 wl = *(const bf16x8*)(&lsW[buf][0] + (size_t)(((tH + 1) * 4 + l4) * 32 + wro) * 8);
        #pragma unroll
        for (int r = 0; r < 2; ++r){
          acc[r][c][mg] = __builtin_amdgcn_mfma_f32_16x16x32_bf16(fa[buf][r][m*2],   wh, acc[r][c][mg], 0, 0, 0);
          acc[r][c][mg] = __builtin_amdgcn_mfma_f32_16x16x32_bf16(fa[buf][r][m*2],   wl, acc[r][c][mg], 0, 0, 0);
          acc[r][c][mg] = __builtin_amdgcn_mfma_f32_16x16x32_bf16(fa[buf][r][m*2+1], wh, acc[r][c][mg], 0, 0, 0);
        }
      }
    }
  };

  // prologue: 3 sets in flight (14 vmem ops per set)
  stageW(0, 0); loadA(0, 0);
  stageW(1, 1); loadA(1, 1);
  stageW(2, 2); loadA(2, 2);
  #pragma unroll
  for (int ks = 0; ks < 10; ++ks){
    const int buf = ks % 3;          // compile-time after full unroll
    if (ks <= 7)      asm volatile("s_waitcnt vmcnt(28)" ::: "memory");
    else if (ks == 8) asm volatile("s_waitcnt vmcnt(14)" ::: "memory");
    else              asm volatile("s_waitcnt vmcnt(0)"  ::: "memory");
    __builtin_amdgcn_sched_barrier(0);
    __builtin_amdgcn_s_barrier();          // lsW[buf] published to all waves
    __builtin_amdgcn_sched_barrier(0);
    compute(buf);
    __builtin_amdgcn_sched_barrier(0);
    __builtin_amdgcn_s_barrier();          // all waves done reading lsW[buf]
    __builtin_amdgcn_sched_barrier(0);
    if (ks + 3 <= 9){ stageW(ks + 3, buf); loadA(ks + 3, buf); }
  }

  #pragma unroll
  for (int c = 0; c < 2; ++c){
    int j = jt * 32 + c * 16 + l15;
    bool jok = j < D;
    float b0=0.f,b1=0.f,b2=0.f,c0=0.f,c1=0.f,c2=0.f;
    if (jok){ b0=bih[j]; b1=bih[j+300]; b2=bih[j+600]; c0=bhh[j]; c1=bhh[j+300]; c2=bhh[j+600]; }
    #pragma unroll
    for (int r = 0; r < 2; ++r){
      #pragma unroll
      for (int q = 0; q < 4; ++q){
        int row = rowBase + wid * 32 + r * 16 + l4 * 4 + q;
        float o = 0.f;
        if (jok){
          float ir = acc[r][c][0][q] + b0, iz = acc[r][c][1][q] + b1, in_ = acc[r][c][2][q] + b2;
          float hr = acc[r][c][3][q] + c0, hz = acc[r][c][4][q] + c1, hn  = acc[r][c][5][q] + c2;
          float rg = 1.f / (1.f + expf(-(ir + hr)));
          float zg = 1.f / (1.f + expf(-(iz + hz)));
          float nn = tanhf(in_ + rg * hn);
          float h = pread(Hh, Hl, (size_t)row * KP + j);
          o = (1.f - zg) * nn + zg * h;
          o = o > 0.f ? o : 0.f;
        }
        if (j < KP) pwrite(Oh, Ol, (size_t)row * KP + j, o);
      }
    }
  }
}

// ---------------- init: planes of emb_atom[x0]+emb_chir[x1] ----------------
__global__ void k_embed2(const int* __restrict__ x, const float* __restrict__ ea,
                         const float* __restrict__ ec, us* __restrict__ hb,
                         us* __restrict__ lb, int N, int total){
  int idx = blockIdx.x * blockDim.x + threadIdx.x;
  if (idx >= total) return;
  int r = idx / KP, j = idx - r * KP;
  float v = (r < N && j < D) ? ea[x[2*r] * D + j] + ec[x[2*r+1] * D + j] : 0.f;
  pwrite(hb, lb, idx, v);
}

// ------- T[c][0..319] = (ge_e1[t]+ge_e2[d]) @ W1b^T, zero-padded ----------
__global__ void k_table(const float* __restrict__ e1, const float* __restrict__ e2,
                        const float* __restrict__ W1, float* __restrict__ T){
  int c = blockIdx.x, t = c / 3, d = c - 3 * (c / 3);
  __shared__ float se[D];
  for (int k = threadIdx.x; k < D; k += blockDim.x) se[k] = e1[t*D + k] + e2[d*D + k];
  __syncthreads();
  for (int j = threadIdx.x; j < KP; j += blockDim.x){
    float s = 0.f;
    if (j < D) for (int k = 0; k < D; ++k) s += se[k] * W1[(size_t)j * 600 + 300 + k];
    T[c * KP + j] = s;
  }
}

// ------- padded fp32 vector table vp[18][320] ------------------------------
__global__ void k_pads(const float* __restrict__ ge_att_l, const float* __restrict__ ge_att_r,
                       const float* __restrict__ gat_att_s, const float* __restrict__ gat_att_d,
                       const float* __restrict__ mol_att_s, const float* __restrict__ mol_att_d,
                       const float* __restrict__ gat_b, const float* __restrict__ mol_b,
                       const float* __restrict__ lin2_W, float* __restrict__ vp){
  int idx = blockIdx.x * blockDim.x + threadIdx.x;
  if (idx >= 18 * KP) return;
  int s = idx / KP, j = idx - s * KP;
  float v = 0.f;
  if (j < D){
    if (s == 0) v = ge_att_l[j];
    else if (s == 1) v = ge_att_r[j];
    else if (s < 6)  v = gat_att_s[(s - 2) * D + j];
    else if (s < 10) v = gat_att_d[(s - 6) * D + j];
    else if (s == 10) v = mol_att_s[j];
    else if (s == 11) v = mol_att_d[j];
    else if (s < 16) v = gat_b[(s - 12) * D + j];
    else if (s == 16) v = mol_b[j];
    else v = lin2_W[j];
  }
  vp[idx] = v;
}

__device__ __forceinline__ void load8f(const float* __restrict__ p, float* v){
  float4 a = *(const float4*)p, b = *(const float4*)(p + 4);
  v[0]=a.x; v[1]=a.y; v[2]=a.z; v[3]=a.w; v[4]=b.x; v[5]=b.y; v[6]=b.z; v[7]=b.w;
}
__device__ __forceinline__ void store8p(us* __restrict__ h, us* __restrict__ l,
                                        size_t ob, const float* v){
  ushort4 h0, h1, l0, l1;
  #pragma unroll
  for (int u = 0; u < 8; ++u){
    us hi = f2bf(v[u]), lo = f2bf(v[u] - bf2f(hi));
    if (u < 4){ ((us*)&h0)[u] = hi; ((us*)&l0)[u] = lo; }
    else      { ((us*)&h1)[u-4] = hi; ((us*)&l1)[u-4] = lo; }
  }
  *(ushort4*)(h + ob) = h0; *(ushort4*)(h + ob + 4) = h1;
  *(ushort4*)(l + ob) = l0; *(ushort4*)(l + ob + 4) = l1;
}

// ---------------- row dot (plane pair, padded vector) ---------------------
__global__ void k_dot2(const us* __restrict__ Ahp, const us* __restrict__ Alp,
                       const float* __restrict__ vp, float* __restrict__ out, int M){
  int w = (blockIdx.x * blockDim.x + threadIdx.x) >> 6;
  int lane = threadIdx.x & 63;
  if (w >= M) return;
  float s = 0.f;
  if (lane < 40){
    int jb = lane * 8;
    size_t b = (size_t)w * KP + jb;
    bf16x8 hv = *(const bf16x8*)(Ahp + b), lv = *(const bf16x8*)(Alp + b);
    float vv[8]; load8f(vp + jb, vv);
    #pragma unroll
    for (int u = 0; u < 8; ++u) s += (bf2f((us)hv[u]) + bf2f((us)lv[u])) * vv[u];
  }
  #pragma unroll
  for (int o = 32; o; o >>= 1) s += __shfl_xor(s, o);
  if (lane == 0) out[w] = s;
}

// ---------------- CSR build ------------------------------------------------
__global__ void k_hist(const int* __restrict__ ei, int E, int* __restrict__ hist){
  int e = blockIdx.x * blockDim.x + threadIdx.x;
  if (e < E) atomicAdd(&hist[ei[E + e]], 1);
}
template<int BS>
__global__ void k_scanA(const int* __restrict__ in, int* __restrict__ out,
                        int* __restrict__ bsum, int n){
  __shared__ int s[BS];
  int t = threadIdx.x, gid = blockIdx.x * BS + t;
  int v = (gid < n) ? in[gid] : 0;
  s[t] = v; __syncthreads();
  for (int o = 1; o < BS; o <<= 1){
    int add = (t >= o) ? s[t - o] : 0;
    __syncthreads();
    s[t] += add;
    __syncthreads();
  }
  if (gid < n) out[gid] = s[t] - v;
  if (t == BS - 1) bsum[blockIdx.x] = s[BS - 1];
}
template<int BS>
__global__ void k_scanB(int* __restrict__ bsum, int nb){
  __shared__ int s[BS];
  int t = threadIdx.x;
  int v = (t < nb) ? bsum[t] : 0;
  s[t] = v; __syncthreads();
  for (int o = 1; o < BS; o <<= 1){
    int add = (t >= o) ? s[t - o] : 0;
    __syncthreads();
    s[t] += add;
    __syncthreads();
  }
  if (t < nb) bsum[t] = s[t] - v;
}
template<int BS>
__global__ void k_scanC(int* __restrict__ out, const int* __restrict__ bsum, int n){
  int gid = blockIdx.x * BS + threadIdx.x;
  if (gid < n) out[gid] += bsum[blockIdx.x];
}
__global__ void k_setN(int* __restrict__ off, int N, int E){ off[N] = E; }
__global__ void k_fill(const int* __restrict__ ei, int E, const int* __restrict__ off,
                       int* __restrict__ cnt, int* __restrict__ lst){
  int e = blockIdx.x * blockDim.x + threadIdx.x;
  if (e >= E) return;
  int d = ei[E + e];
  int p = off[d] + atomicAdd(&cnt[d], 1);
  lst[p] = e;
}
__global__ void k_goff(const int* __restrict__ batch, int N, int G, int* __restrict__ goff){
  int g = blockIdx.x * blockDim.x + threadIdx.x;
  if (g > G) return;
  int lo = 0, hi = N;
  while (lo < hi){ int mid = (lo + hi) >> 1; if (batch[mid] < g) lo = mid + 1; else hi = mid; }
  goff[g] = lo;
}

// ---------------- fused GATEConv attention (online softmax, CSR) ----------
__global__ void k_gate_fused(const us* __restrict__ uh, const us* __restrict__ ul,
                             const float* __restrict__ Tp, const float* __restrict__ att_lp,
                             const float* __restrict__ rvec,
                             const int* __restrict__ ei, const int* __restrict__ ea,
                             const int* __restrict__ off, const int* __restrict__ lst,
                             us* __restrict__ oh, us* __restrict__ ol, int N){
  int d = (blockIdx.x * blockDim.x + threadIdx.x) >> 6;
  int lane = threadIdx.x & 63;
  if (d >= N) return;
  bool act = lane < 40;
  int jb = lane * 8;
  float al[8] = {};
  if (act) load8f(att_lp + jb, al);
  int beg = off[d], deg = off[d + 1] - beg;
  float rd = rvec[d];
  float accv[8] = {}, m = -1e30f, s = 0.f;
  for (int ii = 0; ii <= deg; ++ii){
    int src, c;
    if (ii < deg){ int e = lst[beg + ii]; src = ei[e]; c = ea[2*e] * 3 + ea[2*e + 1]; }
    else { src = d; c = 12; }
    float xv[8] = {}; float part = 0.f;
    if (act){
      size_t ub = (size_t)src * KP + jb;
      bf16x8 hv = *(const bf16x8*)(uh + ub), lv = *(const bf16x8*)(ul + ub);
      float tv[8]; load8f(Tp + c * KP + jb, tv);
      #pragma unroll
      for (int u = 0; u < 8; ++u){
        float v = bf2f((us)hv[u]) + bf2f((us)lv[u]) + tv[u];
        v = v > 0.f ? v : 0.01f * v;
        part += v * al[u];
        xv[u] = v;
      }
    }
    #pragma unroll
    for (int o = 32; o; o >>= 1) part += __shfl_xor(part, o);
    float l = part + rd; l = l > 0.f ? l : 0.01f * l;
    float mn = fmaxf(m, l);
    float sc = expf(m - mn), p = expf(l - mn);
    #pragma unroll
    for (int u = 0; u < 8; ++u) accv[u] = accv[u] * sc + p * xv[u];
    s = s * sc + p; m = mn;
  }
  if (act){
    float inv = 1.f / (s + 1e-16f);
    float v[8];
    #pragma unroll
    for (int u = 0; u < 8; ++u) v[u] = accv[u] * inv;
    store8p(oh, ol, (size_t)d * KP + jb, v);
  }
}

// ---------------- fused GATConv attention (+bias+elu) ---------------------
__global__ void k_gat_fused(const us* __restrict__ xh, const us* __restrict__ xl,
                            const float* __restrict__ as_, const float* __restrict__ ad,
                            const int* __restrict__ ei,
                            const int* __restrict__ off, const int* __restrict__ lst,
                            const float* __restrict__ biasp,
                            us* __restrict__ oh, us* __restrict__ ol, int N){
  int d = (blockIdx.x * blockDim.x + threadIdx.x) >> 6;
  int lane = threadIdx.x & 63;
  if (d >= N) return;
  bool act = lane < 40;
  int jb = lane * 8;
  int beg = off[d], deg = off[d + 1] - beg;
  float add = ad[d];
  float accv[8] = {}, m = -1e30f, s = 0.f;
  for (int ii = 0; ii < deg; ++ii){
    int e = lst[beg + ii];
    int src = ei[e];
    float l = as_[src] + add; l = l > 0.f ? l : 0.2f * l;
    float mn = fmaxf(m, l);
    float sc = expf(m - mn), p = expf(l - mn);
    if (act){
      size_t ub = (size_t)src * KP + jb;
      bf16x8 hv = *(const bf16x8*)(xh + ub), lv = *(const bf16x8*)(xl + ub);
      #pragma unroll
      for (int u = 0; u < 8; ++u)
        accv[u] = accv[u] * sc + p * (bf2f((us)hv[u]) + bf2f((us)lv[u]));
    }
    s = s * sc + p; m = mn;
  }
  if (act){
    float inv = 1.f / (s + 1e-16f);
    float bv[8]; load8f(biasp + jb, bv);
    float v[8];
    #pragma unroll
    for (int u = 0; u < 8; ++u){
      float w = accv[u] * inv + bv[u];
      v[u] = w > 0.f ? w : (expf(w) - 1.f);
    }
    store8p(oh, ol, (size_t)d * KP + jb, v);
  }
}

// ---------------- fused mol attention (+mol_b+elu) ------------------------
__global__ void k_mol_fused(const us* __restrict__ xh, const us* __restrict__ xl,
                            const float* __restrict__ asx, const float* __restrict__ adg,
                            const int* __restrict__ goff, const float* __restrict__ biasp,
                            us* __restrict__ oh, us* __restrict__ ol, int G){
  int g = (blockIdx.x * blockDim.x + threadIdx.x) >> 6;
  int lane = threadIdx.x & 63;
  if (g >= G) return;
  bool act = lane < 40;
  int jb = lane * 8;
  int beg = goff[g], end = goff[g + 1];
  float add = adg[g];
  float accv[8] = {}, m = -1e30f, s = 0.f;
  for (int i = beg; i < end; ++i){
    float l = asx[i] + add; l = l > 0.f ? l : 0.2f * l;
    float mn = fmaxf(m, l);
    float sc = expf(m - mn), p = expf(l - mn);
    if (act){
      size_t ub = (size_t)i * KP + jb;
      bf16x8 hv = *(const bf16x8*)(xh + ub), lv = *(const bf16x8*)(xl + ub);
      #pragma unroll
      for (int u = 0; u < 8; ++u)
        accv[u] = accv[u] * sc + p * (bf2f((us)hv[u]) + bf2f((us)lv[u]));
    }
    s = s * sc + p; m = mn;
  }
  if (act){
    float inv = 1.f / (s + 1e-16f);
    float bv[8]; load8f(biasp + jb, bv);
    float v[8];
    #pragma unroll
    for (int u = 0; u < 8; ++u){
      float w = accv[u] * inv + bv[u];
      v[u] = w > 0.f ? w : (expf(w) - 1.f);
    }
    store8p(oh, ol, (size_t)g * KP + jb, v);
  }
}

// ---------------- segment-sum + relu -> G planes --------------------------
__global__ void k_gsum(const us* __restrict__ xh, const us* __restrict__ xl,
                       const int* __restrict__ goff,
                       us* __restrict__ oh, us* __restrict__ ol, int G){
  int g = (blockIdx.x * blockDim.x + threadIdx.x) >> 6;
  int lane = threadIdx.x & 63;
  if (g >= G) return;
  bool act = lane < 40;
  int jb = lane * 8;
  int beg = goff[g], end = goff[g + 1];
  float a[8] = {};
  if (act){
    for (int i = beg; i < end; ++i){
      size_t ub = (size_t)i * KP + jb;
      bf16x8 hv = *(const bf16x8*)(xh + ub), lv = *(const bf16x8*)(xl + ub);
      #pragma unroll
      for (int u = 0; u < 8; ++u) a[u] += bf2f((us)hv[u]) + bf2f((us)lv[u]);
    }
    float v[8];
    #pragma unroll
    for (int u = 0; u < 8; ++u) v[u] = fmaxf(a[u], 0.f);
    store8p(oh, ol, (size_t)g * KP + jb, v);
  }
}

// ---------------- final: out fp32 + pred ----------------------------------
__global__ void k_final2(const us* __restrict__ Oh, const us* __restrict__ Ol,
                         const float* __restrict__ w2p, const float* __restrict__ b2,
                         float* __restrict__ out, int G){
  int g = (blockIdx.x * blockDim.x + threadIdx.x) >> 6;
  int lane = threadIdx.x & 63;
  if (g >= G) return;
  float s = 0.f;
  if (lane < 40){
    int jb = lane * 8;
    size_t b = (size_t)g * KP + jb;
    bf16x8 hv = *(const bf16x8*)(Oh + b), lv = *(const bf16x8*)(Ol + b);
    float wv[8]; load8f(w2p + jb, wv);
    #pragma unroll
    for (int u = 0; u < 8; ++u){
      float v = bf2f((us)hv[u]) + bf2f((us)lv[u]);
      if (jb + u < D) out[(size_t)g * D + jb + u] = v;
      s += v * wv[u];
    }
  }
  #pragma unroll
  for (int o = 32; o; o >>= 1) s += __shfl_xor(s, o);
  if (lane == 0) out[(size_t)G * D + g] = s + b2[0];
}

// ===========================================================================
extern "C" void kernel_launch(void* const* d_in, const int* in_sizes, int n_in,
                              void* d_out, int out_size, void* d_ws, size_t ws_size,
                              hipStream_t stream){
  (void)n_in; (void)ws_size;
  const int*   x         = (const int*)d_in[0];
  const int*   ei        = (const int*)d_in[1];
  const int*   ea        = (const int*)d_in[2];
  const int*   batch     = (const int*)d_in[3];
  const float* emb_atom  = (const float*)d_in[4];
  const float* emb_chir  = (const float*)d_in[5];
  const float* lin1_W    = (const float*)d_in[6];
  const float* lin1_b    = (const float*)d_in[7];
  const float* ge_e1     = (const float*)d_in[8];
  const float* ge_e2     = (const float*)d_in[9];
  const float* ge_att_l  = (const float*)d_in[10];
  const float* ge_att_r  = (const float*)d_in[11];
  const float* ge_lin1_W = (const float*)d_in[12];
  const float* ge_lin2_W = (const float*)d_in[13];
  const float* ge_bias   = (const float*)d_in[14];
  const float* gat_W     = (const float*)d_in[15];
  const float* gat_att_s = (const float*)d_in[16];
  const float* gat_att_d = (const float*)d_in[17];
  const float* gat_b     = (const float*)d_in[18];
  const float* gru_wih   = (const float*)d_in[19];
  const float* gru_whh   = (const float*)d_in[20];
  const float* gru_bih   = (const float*)d_in[21];
  const float* gru_bhh   = (const float*)d_in[22];
  const float* mol_Ws    = (const float*)d_in[23];
  const float* mol_Wd    = (const float*)d_in[24];
  const float* mol_att_s = (const float*)d_in[25];
  const float* mol_att_d = (const float*)d_in[26];
  const float* mol_b     = (const float*)d_in[27];
  const float* mgru_wih  = (const float*)d_in[28];
  const float* mgru_whh  = (const float*)d_in[29];
  const float* mgru_bih  = (const float*)d_in[30];
  const float* mgru_bhh  = (const float*)d_in[31];
  const float* lin2_W    = (const float*)d_in[32];
  const float* lin2_b    = (const float*)d_in[33];

  const int N  = in_sizes[0] / 2;
  const int E  = in_sizes[1] / 2;
  const int G  = out_size / (D + 1);
  const int Npad = cdiv(N, 128) * 128;
  const int Gpad = cdiv(G, 128) * 128;

  char* base = (char*)d_ws;
  size_t used = 0;
  auto alloc = [&](size_t bytes) -> void* {
    void* p = base + used;
    used += (bytes + 255) & ~(size_t)255;
    return p;
  };
  // three N-row plane pairs
  us* PaH = (us*)alloc((size_t)Npad * KP * 2); us* PaL = (us*)alloc((size_t)Npad * KP * 2);
  us* PbH = (us*)alloc((size_t)Npad * KP * 2); us* PbL = (us*)alloc((size_t)Npad * KP * 2);
  us* PcH = (us*)alloc((size_t)Npad * KP * 2); us* PcL = (us*)alloc((size_t)Npad * KP * 2);
  // three G-row plane pairs
  us* QaH = (us*)alloc((size_t)Gpad * KP * 2); us* QaL = (us*)alloc((size_t)Gpad * KP * 2);
  us* QbH = (us*)alloc((size_t)Gpad * KP * 2); us* QbL = (us*)alloc((size_t)Gpad * KP * 2);
  us* QcH = (us*)alloc((size_t)Gpad * KP * 2); us* QcL = (us*)alloc((size_t)Gpad * KP * 2);
  // small weights (plane pairs, 384 rows)
  auto wsm = [&](void){ return (us*)alloc((size_t)384 * KP * 2); };
  us *wlin1H=wsm(), *wlin1L=wsm(), *wgeuH=wsm(), *wgeuL=wsm(), *wge2H=wsm(), *wge2L=wsm();
  us *wgatH[4], *wgatL[4];
  for (int l = 0; l < 4; ++l){ wgatH[l]=wsm(); wgatL[l]=wsm(); }
  us *wmolSH=wsm(), *wmolSL=wsm(), *wmolDH=wsm(), *wmolDL=wsm();
  // packed GRU weights: 6 sets
  us* Wgru[6];
  for (int l = 0; l < 6; ++l) Wgru[l] = (us*)alloc((size_t)1228800 * 2);
  float* Tt  = (float*)alloc((size_t)18 * KP * 4);
  float* vp  = (float*)alloc((size_t)18 * KP * 4);
  float* rv  = (float*)alloc((size_t)N * 4);
  float* adv = (float*)alloc((size_t)N * 4);
  float* asx = (float*)alloc((size_t)N * 4);
  // CSR
  const int SBS = 512;
  int nblk = cdiv(N, SBS);
  int* hist = (int*)alloc((size_t)N * 4);
  int* cnt  = (int*)alloc((size_t)N * 4);
  int* off  = (int*)alloc((size_t)(N + 1) * 4);
  int* bsum = (int*)alloc((size_t)nblk * 4);
  int* lst  = (int*)alloc((size_t)E * 4);
  int* goff = (int*)alloc((size_t)(G + 1) * 4);

  auto cvt2 = [&](const float* src, int ld, int M, us* hb, us* lb, int Mpad){
    int tot = Mpad * 80;
    k_cvt2<<<cdiv(tot, 256), 256, 0, stream>>>(src, ld, M, hb, lb, tot);
  };
  auto mm_p = [&](const us* ah, const us* al, const us* bh, const us* bl,
                  const float* bias, us* ch, us* cl, int M, int NC, int mode){
    int nwg = cdiv(M, 128) * 3;
    if (mode == 0)      k_mfma3<0><<<nwg, 256, 0, stream>>>(ah, al, bh, bl, bias, ch, cl, M, NC);
    else if (mode == 1) k_mfma3<1><<<nwg, 256, 0, stream>>>(ah, al, bh, bl, bias, ch, cl, M, NC);
    else                k_mfma3<2><<<nwg, 256, 0, stream>>>(ah, al, bh, bl, bias, ch, cl, M, NC);
  };
  auto gru = [&](const us* Ih, const us* Il, const us* Hh, const us* Hl,
                 const us* Wp, const float* bi, const float* bh,
                 us* Oh, us* Ol, int Mpad){
    int nwg = (Mpad / 128) * 10;
    k_gru<<<nwg, 256, 0, stream>>>(Ih, Il, Hh, Hl, Wp, bi, bh, Oh, Ol);
  };

  // ---- CSR build ----
  hipMemsetAsync(hist, 0, (size_t)N * 4, stream);
  k_hist<<<cdiv(E, 256), 256, 0, stream>>>(ei, E, hist);
  k_scanA<SBS><<<nblk, SBS, 0, stream>>>(hist, off, bsum, N);
  k_scanB<SBS><<<1, SBS, 0, stream>>>(bsum, nblk);
  k_scanC<SBS><<<nblk, SBS, 0, stream>>>(off, bsum, N);
  k_setN<<<1, 1, 0, stream>>>(off, N, E);
  hipMemsetAsync(cnt, 0, (size_t)N * 4, stream);
  k_fill<<<cdiv(E, 256), 256, 0, stream>>>(ei, E, off, cnt, lst);
  k_goff<<<cdiv(G + 1, 256), 256, 0, stream>>>(batch, N, G, goff);

  // ---- weights -> planes / packs / padded vectors ----
  cvt2(lin1_W, D, D, wlin1H, wlin1L, 384);
  cvt2(ge_lin1_W, 2 * D, D, wgeuH, wgeuL, 384);
  cvt2(ge_lin2_W, D, D, wge2H, wge2L, 384);
  for (int l = 0; l < 4; ++l) cvt2(gat_W + (size_t)l * D * D, D, D, wgatH[l], wgatL[l], 384);
  cvt2(mol_Ws, D, D, wmolSH, wmolSL, 384);
  cvt2(mol_Wd, D, D, wmolDH, wmolDL, 384);
  for (int l = 0; l < 5; ++l)
    k_wpack<<<1200, 256, 0, stream>>>(gru_wih + (size_t)l * 270000,
                                      gru_whh + (size_t)l * 270000, Wgru[l]);
  k_wpack<<<1200, 256, 0, stream>>>(mgru_wih, mgru_whh, Wgru[5]);
  k_table<<<18, 256, 0, stream>>>(ge_e1, ge_e2, ge_lin1_W, Tt);
  k_pads<<<cdiv(18 * KP, 256), 256, 0, stream>>>(ge_att_l, ge_att_r, gat_att_s, gat_att_d,
                                                 mol_att_s, mol_att_d, gat_b, mol_b, lin2_W, vp);

  // ---- init features ----
  k_embed2<<<cdiv(Npad * KP, 256), 256, 0, stream>>>(x, emb_atom, emb_chir, PaH, PaL, N, Npad * KP);
  mm_p(PaH, PaL, wlin1H, wlin1L, lin1_b, PbH, PbL, N, D, 1);       // xf -> Pb

  // ---- GATEConv ----
  mm_p(PbH, PbL, wgeuH, wgeuL, nullptr, PaH, PaL, N, D, 0);        // u -> Pa
  k_dot2<<<cdiv(N, 4), 256, 0, stream>>>(PbH, PbL, vp + 1 * KP, rv, N);
  k_gate_fused<<<cdiv(N, 4), 256, 0, stream>>>(PaH, PaL, Tt, vp, rv,
                                               ei, ea, off, lst, PcH, PcL, N);
  mm_p(PcH, PcL, wge2H, wge2L, ge_bias, PaH, PaL, N, D, 2);        // elu(h) -> Pa
  gru(PaH, PaL, PbH, PbL, Wgru[0], gru_bih, gru_bhh, PcH, PcL, Npad);   // xf -> Pc

  us *xfH = PcH, *xfL = PcL, *aH = PaH, *aL = PaL, *bH = PbH, *bL = PbL;
  // ---- GATConv layers 1..4 ----
  for (int l = 0; l < 4; ++l){
    mm_p(xfH, xfL, wgatH[l], wgatL[l], nullptr, aH, aL, N, D, 0);  // xw -> a
    k_dot2<<<cdiv(N, 4), 256, 0, stream>>>(aH, aL, vp + (2 + l) * KP, rv, N);
    k_dot2<<<cdiv(N, 4), 256, 0, stream>>>(aH, aL, vp + (6 + l) * KP, adv, N);
    k_gat_fused<<<cdiv(N, 4), 256, 0, stream>>>(aH, aL, rv, adv, ei, off, lst,
                                                vp + (12 + l) * KP, bH, bL, N);
    gru(bH, bL, xfH, xfL, Wgru[l + 1],
        gru_bih + (l + 1) * 900, gru_bhh + (l + 1) * 900, aH, aL, Npad);  // xf' -> a
    us* th = xfH; us* tl = xfL;
    xfH = aH; xfL = aL; aH = th; aL = tl;
  }

  // ---- attentive readout ----
  k_gsum<<<cdiv(G, 4), 256, 0, stream>>>(xfH, xfL, goff, QaH, QaL, G);      // OUT -> Qa
  mm_p(xfH, xfL, wmolSH, wmolSL, nullptr, aH, aL, N, D, 0);                 // xs -> a (pinned)
  k_dot2<<<cdiv(N, 4), 256, 0, stream>>>(aH, aL, vp + 10 * KP, asx, N);
  us *outH = QaH, *outL = QaL, *sgH = QbH, *sgL = QbL, *xdH = QcH, *xdL = QcL;
  for (int t = 0; t < 3; ++t){
    mm_p(outH, outL, wmolDH, wmolDL, nullptr, xdH, xdL, G, D, 0);           // xd
    k_dot2<<<cdiv(G, 4), 256, 0, stream>>>(xdH, xdL, vp + 11 * KP, adv, G);
    k_mol_fused<<<cdiv(G, 4), 256, 0, stream>>>(aH, aL, asx, adv, goff,
                                                vp + 16 * KP, sgH, sgL, G);
    gru(sgH, sgL, outH, outL, Wgru[5], mgru_bih, mgru_bhh, xdH, xdL, Gpad); // out' -> xd
    us* th = outH; us* tl = outL;
    outH = xdH; outL = xdL; xdH = th; xdL = tl;
  }
  k_final2<<<cdiv(G, 4), 256, 0, stream>>>(outH, outL, vp + 17 * KP, lin2_b, (float*)d_out, G);
}

// Round 13
// 2857.983 us; speedup vs baseline: 1.0753x; 1.0753x over previous
//
#include <hip/hip_runtime.h>

constexpr int D = 300;
constexpr int KP = 320;   // K padded to multiple of 32

static inline int cdiv(int a, int b){ return (a + b - 1) / b; }

__device__ __forceinline__ unsigned short f2bf(float f){
  unsigned u = __float_as_uint(f);
  unsigned r = (u + 0x7fffu + ((u >> 16) & 1u)) >> 16;
  return (unsigned short)r;
}
__device__ __forceinline__ float bf2f(unsigned short h){
  return __uint_as_float((unsigned)h << 16);
}
__device__ __forceinline__ float pread(const unsigned short* __restrict__ h,
                                       const unsigned short* __restrict__ l, size_t i){
  return bf2f(h[i]) + bf2f(l[i]);
}
__device__ __forceinline__ void pwrite(unsigned short* __restrict__ h,
                                       unsigned short* __restrict__ l, size_t i, float v){
  unsigned short hi = f2bf(v);
  h[i] = hi; l[i] = f2bf(v - bf2f(hi));
}
// bijective XCD-chunk swizzle (m204): hardware bid -> chunked work id
__device__ __forceinline__ int xcd_chunk(int bid, int nwg){
  int q = nwg >> 3, r = nwg & 7;
  int x = bid & 7, i = bid >> 3;
  return (x < r ? x * (q + 1) : r * (q + 1) + (x - r) * q) + i;
}

typedef __attribute__((ext_vector_type(8))) short bf16x8;
typedef __attribute__((ext_vector_type(4))) float f32x4;
typedef unsigned short us;

// ------- fp32 [M x 300] (row stride ld) -> hi/lo bf16 planes [Mpad x 320] ---
__global__ void k_cvt2(const float* __restrict__ src, int ld, int M,
                       us* __restrict__ hb, us* __restrict__ lb, int total){
  int idx = blockIdx.x * blockDim.x + threadIdx.x;
  if (idx >= total) return;
  int r = idx / 80, k4 = (idx - r * 80) * 4;
  const float* row = src + (size_t)r * ld;
  bool rm = r < M;
  ushort4 oh, ol;
  float x;
  x = (rm && k4 + 0 < D) ? row[k4 + 0] : 0.f; oh.x = f2bf(x); ol.x = f2bf(x - bf2f(oh.x));
  x = (rm && k4 + 1 < D) ? row[k4 + 1] : 0.f; oh.y = f2bf(x); ol.y = f2bf(x - bf2f(oh.y));
  x = (rm && k4 + 2 < D) ? row[k4 + 2] : 0.f; oh.z = f2bf(x); ol.z = f2bf(x - bf2f(oh.z));
  x = (rm && k4 + 3 < D) ? row[k4 + 3] : 0.f; oh.w = f2bf(x); ol.w = f2bf(x - bf2f(oh.w));
  *(ushort4*)(hb + (size_t)r * KP + k4) = oh;
  *(ushort4*)(lb + (size_t)r * KP + k4) = ol;
}

// ------- GRU weight pack: [jt(10)][ks(10)][t(12)][kg(4)][row(32)][8 halves] --
__global__ void k_wpack(const float* __restrict__ Wih, const float* __restrict__ Whh,
                        us* __restrict__ out){
  int idx = blockIdx.x * blockDim.x + threadIdx.x;
  if (idx >= 307200) return;
  int h4 = idx * 4;
  int jtks = h4 / 12288;
  int within = h4 - jtks * 12288;
  int jt = jtks / 10, ks = jtks - (jtks / 10) * 10;
  int t = within >> 10;
  int w2 = within & 1023;
  int kg = w2 >> 8;
  int row = (w2 >> 3) & 31;
  int h0 = w2 & 7;
  int m = t / 6, g = (t >> 1) % 3, p = t & 1;
  int j = jt * 32 + row;
  const float* W = m ? Whh : Wih;
  ushort4 o;
  us* po = (us*)&o;
  #pragma unroll
  for (int u = 0; u < 4; ++u){
    int k = ks * 32 + kg * 8 + h0 + u;
    float v = (j < D && k < D) ? W[(size_t)(g * D + j) * D + k] : 0.f;
    us hi = f2bf(v);
    po[u] = p ? f2bf(v - bf2f(hi)) : hi;
  }
  *(ushort4*)(out + h4) = o;
}

// ------- bf16x3 MFMA gemm (single-buffer LDS) ------------------------------
template<int MODE>
__global__ void k_mfma3(const us* __restrict__ Ah, const us* __restrict__ Al,
                        const us* __restrict__ Bh, const us* __restrict__ Bl,
                        const float* __restrict__ bias,
                        us* __restrict__ Ch, us* __restrict__ Cl,
                        int M, int NC){
  __shared__ short ls[4][4096];   // Ah,Al,Bh,Bl tiles: [kg(4)][row(128)][8]
  const int tid = threadIdx.x;
  const int lane = tid & 63;
  const int wid = tid >> 6, wr = wid >> 1, wc = wid & 1;
  int work = xcd_chunk(blockIdx.x, gridDim.x);
  const int rowBase = (work / 3) * 128, colBase = (work - (work / 3) * 3) * 128;
  const int l15 = lane & 15, l4 = lane >> 4;
  f32x4 acc[4][4] = {};
  const us* gsrc[4] = {Ah, Al, Bh, Bl};

  for (int k0 = 0; k0 < KP; k0 += 32){
    #pragma unroll
    for (int t = 0; t < 4; ++t){
      int base = (t < 2) ? rowBase : colBase;
      #pragma unroll
      for (int s = 0; s < 2; ++s){
        int lin = s * 256 + tid;
        int kg = lin >> 7, row = lin & 127;
        const us* g = gsrc[t] + (size_t)(base + row) * KP + k0 + kg * 8;
        short* lb = &ls[t][0] + (size_t)(s * 256 + (tid & ~63)) * 8;
        __builtin_amdgcn_global_load_lds((const __attribute__((address_space(1))) unsigned*)g,
                                         (__attribute__((address_space(3))) unsigned*)lb, 16, 0, 0);
      }
    }
    __syncthreads();
    bf16x8 fbh[4], fbl[4];
    #pragma unroll
    for (int j = 0; j < 4; ++j){
      int bi = l4 * 128 + wc * 64 + j * 16 + l15;
      fbh[j] = *(const bf16x8*)(&ls[2][0] + (size_t)bi * 8);
      fbl[j] = *(const bf16x8*)(&ls[3][0] + (size_t)bi * 8);
    }
    #pragma unroll
    for (int i = 0; i < 4; ++i){
      int ai = l4 * 128 + wr * 64 + i * 16 + l15;
      bf16x8 fah = *(const bf16x8*)(&ls[0][0] + (size_t)ai * 8);
      bf16x8 fal = *(const bf16x8*)(&ls[1][0] + (size_t)ai * 8);
      #pragma unroll
      for (int j = 0; j < 4; ++j){
        acc[i][j] = __builtin_amdgcn_mfma_f32_16x16x32_bf16(fah, fbh[j], acc[i][j], 0, 0, 0);
        acc[i][j] = __builtin_amdgcn_mfma_f32_16x16x32_bf16(fah, fbl[j], acc[i][j], 0, 0, 0);
        acc[i][j] = __builtin_amdgcn_mfma_f32_16x16x32_bf16(fal, fbh[j], acc[i][j], 0, 0, 0);
      }
    }
    __syncthreads();
  }

  #pragma unroll
  for (int i = 0; i < 4; ++i){
    #pragma unroll
    for (int q = 0; q < 4; ++q){
      int r = rowBase + wr * 64 + i * 16 + l4 * 4 + q;
      if (r >= M) continue;
      #pragma unroll
      for (int j = 0; j < 4; ++j){
        int c = colBase + wc * 64 + j * 16 + l15;
        if (c >= KP) continue;
        size_t o = (size_t)r * KP + c;
        if (c >= NC){ Ch[o] = 0; Cl[o] = 0; continue; }
        float v = acc[i][j][q];
        if (MODE) v += bias[c];
        if (MODE == 1) v = v > 0.f ? v : 0.01f * v;
        if (MODE == 2) v = v > 0.f ? v : (expf(v) - 1.f);
        pwrite(Ch, Cl, o, v);
      }
    }
  }
}

// ---------------- GRU v3: reg-A dbuf + LDS-W dbuf, pipelined ---------------
__global__ __launch_bounds__(256, 2) void k_gru(
    const us* __restrict__ Ih, const us* __restrict__ Il,
    const us* __restrict__ Hh, const us* __restrict__ Hl,
    const us* __restrict__ Wp,
    const float* __restrict__ bih, const float* __restrict__ bhh,
    us* __restrict__ Oh, us* __restrict__ Ol){
  __shared__ short lsW[2][12288];   // [t(12)][kg(4)][row(32)][8]
  const int tid = threadIdx.x, lane = tid & 63, wid = tid >> 6;
  const int l15 = lane & 15, l4 = lane >> 4;
  int work = xcd_chunk(blockIdx.x, gridDim.x);
  const int rt = work / 10, jt = work - rt * 10;
  const int rowBase = rt * 128;
  f32x4 acc[2][2][6] = {};
  const us* asrc[4] = {Ih, Il, Hh, Hl};
  bf16x8 fa[2][2][4];   // [buf][r][tensor]

  auto loadA = [&](int ks, int buf){
    int k0 = ks * 32;
    #pragma unroll
    for (int r = 0; r < 2; ++r){
      size_t base = (size_t)(rowBase + wid * 32 + r * 16 + l15) * KP + k0 + l4 * 8;
      #pragma unroll
      for (int t = 0; t < 4; ++t)
        fa[buf][r][t] = *(const bf16x8*)(asrc[t] + base);
    }
  };
  auto stageW = [&](int ks, int buf){
    const us* wsrc = Wp + (size_t)(jt * 10 + ks) * 12288;
    #pragma unroll
    for (int s = 0; s < 6; ++s){
      int lin = s * 256 + tid;
      __builtin_amdgcn_global_load_lds(
        (const __attribute__((address_space(1))) unsigned*)(wsrc + (size_t)lin * 8),
        (__attribute__((address_space(3))) unsigned*)(&lsW[buf][0] + (size_t)(s * 256 + (tid & ~63)) * 8),
        16, 0, 0);
    }
  };
  auto compute = [&](int buf){
    #pragma unroll
    for (int c = 0; c < 2; ++c){
      #pragma unroll
      for (int mg = 0; mg < 6; ++mg){
        const int m = mg / 3, g = mg % 3, tH = m * 6 + g * 2;
        int wro = c * 16 + l15;
        bf16x8 wh = *(const bf16x8*)(&lsW[buf][0] + (size_t)((tH * 4 + l4) * 32 + wro) * 8);
        bf16x8 wl = *(const bf16x8*)(&lsW[buf][0] + (size_t)(((tH + 1) * 4 + l4) * 32 + wro) * 8);
        #pragma unroll
        for (int r = 0; r < 2; ++r){
          acc[r][c][mg] = __builtin_amdgcn_mfma_f32_16x16x32_bf16(fa[buf][r][m*2],   wh, acc[r][c][mg], 0, 0, 0);
          acc[r][c][mg] = __builtin_amdgcn_mfma_f32_16x16x32_bf16(fa[buf][r][m*2],   wl, acc[r][c][mg], 0, 0, 0);
          acc[r][c][mg] = __builtin_amdgcn_mfma_f32_16x16x32_bf16(fa[buf][r][m*2+1], wh, acc[r][c][mg], 0, 0, 0);
        }
      }
    }
  };

  loadA(0, 0); stageW(0, 0);
  __syncthreads();
  for (int ks2 = 0; ks2 < 5; ++ks2){
    int ks = ks2 * 2;
    if (ks < 9){ loadA(ks + 1, 1); stageW(ks + 1, 1); }
    compute(0);
    __syncthreads();
    if (ks + 2 <= 9){ loadA(ks + 2, 0); stageW(ks + 2, 0); }
    compute(1);
    __syncthreads();
  }

  #pragma unroll
  for (int c = 0; c < 2; ++c){
    int j = jt * 32 + c * 16 + l15;
    bool jok = j < D;
    float b0=0.f,b1=0.f,b2=0.f,c0=0.f,c1=0.f,c2=0.f;
    if (jok){ b0=bih[j]; b1=bih[j+300]; b2=bih[j+600]; c0=bhh[j]; c1=bhh[j+300]; c2=bhh[j+600]; }
    #pragma unroll
    for (int r = 0; r < 2; ++r){
      #pragma unroll
      for (int q = 0; q < 4; ++q){
        int row = rowBase + wid * 32 + r * 16 + l4 * 4 + q;
        float o = 0.f;
        if (jok){
          float ir = acc[r][c][0][q] + b0, iz = acc[r][c][1][q] + b1, in_ = acc[r][c][2][q] + b2;
          float hr = acc[r][c][3][q] + c0, hz = acc[r][c][4][q] + c1, hn  = acc[r][c][5][q] + c2;
          float rg = 1.f / (1.f + expf(-(ir + hr)));
          float zg = 1.f / (1.f + expf(-(iz + hz)));
          float nn = tanhf(in_ + rg * hn);
          float h = pread(Hh, Hl, (size_t)row * KP + j);
          o = (1.f - zg) * nn + zg * h;
          o = o > 0.f ? o : 0.f;
        }
        if (j < KP) pwrite(Oh, Ol, (size_t)row * KP + j, o);
      }
    }
  }
}

// ---------------- init: planes of emb_atom[x0]+emb_chir[x1] ----------------
__global__ void k_embed2(const int* __restrict__ x, const float* __restrict__ ea,
                         const float* __restrict__ ec, us* __restrict__ hb,
                         us* __restrict__ lb, int N, int total){
  int idx = blockIdx.x * blockDim.x + threadIdx.x;
  if (idx >= total) return;
  int r = idx / KP, j = idx - r * KP;
  float v = (r < N && j < D) ? ea[x[2*r] * D + j] + ec[x[2*r+1] * D + j] : 0.f;
  pwrite(hb, lb, idx, v);
}

// ------- T[c][0..319] = (ge_e1[t]+ge_e2[d]) @ W1b^T, zero-padded ----------
__global__ void k_table(const float* __restrict__ e1, const float* __restrict__ e2,
                        const float* __restrict__ W1, float* __restrict__ T){
  int c = blockIdx.x, t = c / 3, d = c - 3 * (c / 3);
  __shared__ float se[D];
  for (int k = threadIdx.x; k < D; k += blockDim.x) se[k] = e1[t*D + k] + e2[d*D + k];
  __syncthreads();
  for (int j = threadIdx.x; j < KP; j += blockDim.x){
    float s = 0.f;
    if (j < D) for (int k = 0; k < D; ++k) s += se[k] * W1[(size_t)j * 600 + 300 + k];
    T[c * KP + j] = s;
  }
}

// ------- padded fp32 vector table vp[18][320] ------------------------------
__global__ void k_pads(const float* __restrict__ ge_att_l, const float* __restrict__ ge_att_r,
                       const float* __restrict__ gat_att_s, const float* __restrict__ gat_att_d,
                       const float* __restrict__ mol_att_s, const float* __restrict__ mol_att_d,
                       const float* __restrict__ gat_b, const float* __restrict__ mol_b,
                       const float* __restrict__ lin2_W, float* __restrict__ vp){
  int idx = blockIdx.x * blockDim.x + threadIdx.x;
  if (idx >= 18 * KP) return;
  int s = idx / KP, j = idx - s * KP;
  float v = 0.f;
  if (j < D){
    if (s == 0) v = ge_att_l[j];
    else if (s == 1) v = ge_att_r[j];
    else if (s < 6)  v = gat_att_s[(s - 2) * D + j];
    else if (s < 10) v = gat_att_d[(s - 6) * D + j];
    else if (s == 10) v = mol_att_s[j];
    else if (s == 11) v = mol_att_d[j];
    else if (s < 16) v = gat_b[(s - 12) * D + j];
    else if (s == 16) v = mol_b[j];
    else v = lin2_W[j];
  }
  vp[idx] = v;
}

__device__ __forceinline__ void load8f(const float* __restrict__ p, float* v){
  float4 a = *(const float4*)p, b = *(const float4*)(p + 4);
  v[0]=a.x; v[1]=a.y; v[2]=a.z; v[3]=a.w; v[4]=b.x; v[5]=b.y; v[6]=b.z; v[7]=b.w;
}
__device__ __forceinline__ void store8p(us* __restrict__ h, us* __restrict__ l,
                                        size_t ob, const float* v){
  ushort4 h0, h1, l0, l1;
  #pragma unroll
  for (int u = 0; u < 8; ++u){
    us hi = f2bf(v[u]), lo = f2bf(v[u] - bf2f(hi));
    if (u < 4){ ((us*)&h0)[u] = hi; ((us*)&l0)[u] = lo; }
    else      { ((us*)&h1)[u-4] = hi; ((us*)&l1)[u-4] = lo; }
  }
  *(ushort4*)(h + ob) = h0; *(ushort4*)(h + ob + 4) = h1;
  *(ushort4*)(l + ob) = l0; *(ushort4*)(l + ob + 4) = l1;
}

// ---------------- row dot (plane pair, padded vector) ---------------------
__global__ void k_dot2(const us* __restrict__ Ahp, const us* __restrict__ Alp,
                       const float* __restrict__ vp, float* __restrict__ out, int M){
  int w = (blockIdx.x * blockDim.x + threadIdx.x) >> 6;
  int lane = threadIdx.x & 63;
  if (w >= M) return;
  float s = 0.f;
  if (lane < 40){
    int jb = lane * 8;
    size_t b = (size_t)w * KP + jb;
    bf16x8 hv = *(const bf16x8*)(Ahp + b), lv = *(const bf16x8*)(Alp + b);
    float vv[8]; load8f(vp + jb, vv);
    #pragma unroll
    for (int u = 0; u < 8; ++u) s += (bf2f((us)hv[u]) + bf2f((us)lv[u])) * vv[u];
  }
  #pragma unroll
  for (int o = 32; o; o >>= 1) s += __shfl_xor(s, o);
  if (lane == 0) out[w] = s;
}

// ---------------- CSR build ------------------------------------------------
__global__ void k_hist(const int* __restrict__ ei, int E, int* __restrict__ hist){
  int e = blockIdx.x * blockDim.x + threadIdx.x;
  if (e < E) atomicAdd(&hist[ei[E + e]], 1);
}
template<int BS>
__global__ void k_scanA(const int* __restrict__ in, int* __restrict__ out,
                        int* __restrict__ bsum, int n){
  __shared__ int s[BS];
  int t = threadIdx.x, gid = blockIdx.x * BS + t;
  int v = (gid < n) ? in[gid] : 0;
  s[t] = v; __syncthreads();
  for (int o = 1; o < BS; o <<= 1){
    int add = (t >= o) ? s[t - o] : 0;
    __syncthreads();
    s[t] += add;
    __syncthreads();
  }
  if (gid < n) out[gid] = s[t] - v;
  if (t == BS - 1) bsum[blockIdx.x] = s[BS - 1];
}
template<int BS>
__global__ void k_scanB(int* __restrict__ bsum, int nb){
  __shared__ int s[BS];
  int t = threadIdx.x;
  int v = (t < nb) ? bsum[t] : 0;
  s[t] = v; __syncthreads();
  for (int o = 1; o < BS; o <<= 1){
    int add = (t >= o) ? s[t - o] : 0;
    __syncthreads();
    s[t] += add;
    __syncthreads();
  }
  if (t < nb) bsum[t] = s[t] - v;
}
template<int BS>
__global__ void k_scanC(int* __restrict__ out, const int* __restrict__ bsum, int n){
  int gid = blockIdx.x * BS + threadIdx.x;
  if (gid < n) out[gid] += bsum[blockIdx.x];
}
__global__ void k_setN(int* __restrict__ off, int N, int E){ off[N] = E; }
__global__ void k_fill(const int* __restrict__ ei, int E, const int* __restrict__ off,
                       int* __restrict__ cnt, int* __restrict__ lst){
  int e = blockIdx.x * blockDim.x + threadIdx.x;
  if (e >= E) return;
  int d = ei[E + e];
  int p = off[d] + atomicAdd(&cnt[d], 1);
  lst[p] = e;
}
__global__ void k_goff(const int* __restrict__ batch, int N, int G, int* __restrict__ goff){
  int g = blockIdx.x * blockDim.x + threadIdx.x;
  if (g > G) return;
  int lo = 0, hi = N;
  while (lo < hi){ int mid = (lo + hi) >> 1; if (batch[mid] < g) lo = mid + 1; else hi = mid; }
  goff[g] = lo;
}

// ---------------- fused GATEConv attention (online softmax, CSR) ----------
__global__ void k_gate_fused(const us* __restrict__ uh, const us* __restrict__ ul,
                             const float* __restrict__ Tp, const float* __restrict__ att_lp,
                             const float* __restrict__ rvec,
                             const int* __restrict__ ei, const int* __restrict__ ea,
                             const int* __restrict__ off, const int* __restrict__ lst,
                             us* __restrict__ oh, us* __restrict__ ol, int N){
  int d = (blockIdx.x * blockDim.x + threadIdx.x) >> 6;
  int lane = threadIdx.x & 63;
  if (d >= N) return;
  bool act = lane < 40;
  int jb = lane * 8;
  float al[8] = {};
  if (act) load8f(att_lp + jb, al);
  int beg = off[d], deg = off[d + 1] - beg;
  float rd = rvec[d];
  float accv[8] = {}, m = -1e30f, s = 0.f;
  for (int ii = 0; ii <= deg; ++ii){
    int src, c;
    if (ii < deg){ int e = lst[beg + ii]; src = ei[e]; c = ea[2*e] * 3 + ea[2*e + 1]; }
    else { src = d; c = 12; }
    float xv[8] = {}; float part = 0.f;
    if (act){
      size_t ub = (size_t)src * KP + jb;
      bf16x8 hv = *(const bf16x8*)(uh + ub), lv = *(const bf16x8*)(ul + ub);
      float tv[8]; load8f(Tp + c * KP + jb, tv);
      #pragma unroll
      for (int u = 0; u < 8; ++u){
        float v = bf2f((us)hv[u]) + bf2f((us)lv[u]) + tv[u];
        v = v > 0.f ? v : 0.01f * v;
        part += v * al[u];
        xv[u] = v;
      }
    }
    #pragma unroll
    for (int o = 32; o; o >>= 1) part += __shfl_xor(part, o);
    float l = part + rd; l = l > 0.f ? l : 0.01f * l;
    float mn = fmaxf(m, l);
    float sc = expf(m - mn), p = expf(l - mn);
    #pragma unroll
    for (int u = 0; u < 8; ++u) accv[u] = accv[u] * sc + p * xv[u];
    s = s * sc + p; m = mn;
  }
  if (act){
    float inv = 1.f / (s + 1e-16f);
    float v[8];
    #pragma unroll
    for (int u = 0; u < 8; ++u) v[u] = accv[u] * inv;
    store8p(oh, ol, (size_t)d * KP + jb, v);
  }
}

// ---------------- fused GATConv attention (+bias+elu) ---------------------
__global__ void k_gat_fused(const us* __restrict__ xh, const us* __restrict__ xl,
                            const float* __restrict__ as_, const float* __restrict__ ad,
                            const int* __restrict__ ei,
                            const int* __restrict__ off, const int* __restrict__ lst,
                            const float* __restrict__ biasp,
                            us* __restrict__ oh, us* __restrict__ ol, int N){
  int d = (blockIdx.x * blockDim.x + threadIdx.x) >> 6;
  int lane = threadIdx.x & 63;
  if (d >= N) return;
  bool act = lane < 40;
  int jb = lane * 8;
  int beg = off[d], deg = off[d + 1] - beg;
  float add = ad[d];
  float accv[8] = {}, m = -1e30f, s = 0.f;
  for (int ii = 0; ii < deg; ++ii){
    int e = lst[beg + ii];
    int src = ei[e];
    float l = as_[src] + add; l = l > 0.f ? l : 0.2f * l;
    float mn = fmaxf(m, l);
    float sc = expf(m - mn), p = expf(l - mn);
    if (act){
      size_t ub = (size_t)src * KP + jb;
      bf16x8 hv = *(const bf16x8*)(xh + ub), lv = *(const bf16x8*)(xl + ub);
      #pragma unroll
      for (int u = 0; u < 8; ++u)
        accv[u] = accv[u] * sc + p * (bf2f((us)hv[u]) + bf2f((us)lv[u]));
    }
    s = s * sc + p; m = mn;
  }
  if (act){
    float inv = 1.f / (s + 1e-16f);
    float bv[8]; load8f(biasp + jb, bv);
    float v[8];
    #pragma unroll
    for (int u = 0; u < 8; ++u){
      float w = accv[u] * inv + bv[u];
      v[u] = w > 0.f ? w : (expf(w) - 1.f);
    }
    store8p(oh, ol, (size_t)d * KP + jb, v);
  }
}

// ---------------- fused mol attention (+mol_b+elu) ------------------------
__global__ void k_mol_fused(const us* __restrict__ xh, const us* __restrict__ xl,
                            const float* __restrict__ asx, const float* __restrict__ adg,
                            const int* __restrict__ goff, const float* __restrict__ biasp,
                            us* __restrict__ oh, us* __restrict__ ol, int G){
  int g = (blockIdx.x * blockDim.x + threadIdx.x) >> 6;
  int lane = threadIdx.x & 63;
  if (g >= G) return;
  bool act = lane < 40;
  int jb = lane * 8;
  int beg = goff[g], end = goff[g + 1];
  float add = adg[g];
  float accv[8] = {}, m = -1e30f, s = 0.f;
  for (int i = beg; i < end; ++i){
    float l = asx[i] + add; l = l > 0.f ? l : 0.2f * l;
    float mn = fmaxf(m, l);
    float sc = expf(m - mn), p = expf(l - mn);
    if (act){
      size_t ub = (size_t)i * KP + jb;
      bf16x8 hv = *(const bf16x8*)(xh + ub), lv = *(const bf16x8*)(xl + ub);
      #pragma unroll
      for (int u = 0; u < 8; ++u)
        accv[u] = accv[u] * sc + p * (bf2f((us)hv[u]) + bf2f((us)lv[u]));
    }
    s = s * sc + p; m = mn;
  }
  if (act){
    float inv = 1.f / (s + 1e-16f);
    float bv[8]; load8f(biasp + jb, bv);
    float v[8];
    #pragma unroll
    for (int u = 0; u < 8; ++u){
      float w = accv[u] * inv + bv[u];
      v[u] = w > 0.f ? w : (expf(w) - 1.f);
    }
    store8p(oh, ol, (size_t)g * KP + jb, v);
  }
}

// ---------------- segment-sum + relu -> G planes --------------------------
__global__ void k_gsum(const us* __restrict__ xh, const us* __restrict__ xl,
                       const int* __restrict__ goff,
                       us* __restrict__ oh, us* __restrict__ ol, int G){
  int g = (blockIdx.x * blockDim.x + threadIdx.x) >> 6;
  int lane = threadIdx.x & 63;
  if (g >= G) return;
  bool act = lane < 40;
  int jb = lane * 8;
  int beg = goff[g], end = goff[g + 1];
  float a[8] = {};
  if (act){
    for (int i = beg; i < end; ++i){
      size_t ub = (size_t)i * KP + jb;
      bf16x8 hv = *(const bf16x8*)(xh + ub), lv = *(const bf16x8*)(xl + ub);
      #pragma unroll
      for (int u = 0; u < 8; ++u) a[u] += bf2f((us)hv[u]) + bf2f((us)lv[u]);
    }
    float v[8];
    #pragma unroll
    for (int u = 0; u < 8; ++u) v[u] = fmaxf(a[u], 0.f);
    store8p(oh, ol, (size_t)g * KP + jb, v);
  }
}

// ---------------- final: out fp32 + pred ----------------------------------
__global__ void k_final2(const us* __restrict__ Oh, const us* __restrict__ Ol,
                         const float* __restrict__ w2p, const float* __restrict__ b2,
                         float* __restrict__ out, int G){
  int g = (blockIdx.x * blockDim.x + threadIdx.x) >> 6;
  int lane = threadIdx.x & 63;
  if (g >= G) return;
  float s = 0.f;
  if (lane < 40){
    int jb = lane * 8;
    size_t b = (size_t)g * KP + jb;
    bf16x8 hv = *(const bf16x8*)(Oh + b), lv = *(const bf16x8*)(Ol + b);
    float wv[8]; load8f(w2p + jb, wv);
    #pragma unroll
    for (int u = 0; u < 8; ++u){
      float v = bf2f((us)hv[u]) + bf2f((us)lv[u]);
      if (jb + u < D) out[(size_t)g * D + jb + u] = v;
      s += v * wv[u];
    }
  }
  #pragma unroll
  for (int o = 32; o; o >>= 1) s += __shfl_xor(s, o);
  if (lane == 0) out[(size_t)G * D + g] = s + b2[0];
}

// ===========================================================================
extern "C" void kernel_launch(void* const* d_in, const int* in_sizes, int n_in,
                              void* d_out, int out_size, void* d_ws, size_t ws_size,
                              hipStream_t stream){
  (void)n_in; (void)ws_size;
  const int*   x         = (const int*)d_in[0];
  const int*   ei        = (const int*)d_in[1];
  const int*   ea        = (const int*)d_in[2];
  const int*   batch     = (const int*)d_in[3];
  const float* emb_atom  = (const float*)d_in[4];
  const float* emb_chir  = (const float*)d_in[5];
  const float* lin1_W    = (const float*)d_in[6];
  const float* lin1_b    = (const float*)d_in[7];
  const float* ge_e1     = (const float*)d_in[8];
  const float* ge_e2     = (const float*)d_in[9];
  const float* ge_att_l  = (const float*)d_in[10];
  const float* ge_att_r  = (const float*)d_in[11];
  const float* ge_lin1_W = (const float*)d_in[12];
  const float* ge_lin2_W = (const float*)d_in[13];
  const float* ge_bias   = (const float*)d_in[14];
  const float* gat_W     = (const float*)d_in[15];
  const float* gat_att_s = (const float*)d_in[16];
  const float* gat_att_d = (const float*)d_in[17];
  const float* gat_b     = (const float*)d_in[18];
  const float* gru_wih   = (const float*)d_in[19];
  const float* gru_whh   = (const float*)d_in[20];
  const float* gru_bih   = (const float*)d_in[21];
  const float* gru_bhh   = (const float*)d_in[22];
  const float* mol_Ws    = (const float*)d_in[23];
  const float* mol_Wd    = (const float*)d_in[24];
  const float* mol_att_s = (const float*)d_in[25];
  const float* mol_att_d = (const float*)d_in[26];
  const float* mol_b     = (const float*)d_in[27];
  const float* mgru_wih  = (const float*)d_in[28];
  const float* mgru_whh  = (const float*)d_in[29];
  const float* mgru_bih  = (const float*)d_in[30];
  const float* mgru_bhh  = (const float*)d_in[31];
  const float* lin2_W    = (const float*)d_in[32];
  const float* lin2_b    = (const float*)d_in[33];

  const int N  = in_sizes[0] / 2;
  const int E  = in_sizes[1] / 2;
  const int G  = out_size / (D + 1);
  const int Npad = cdiv(N, 128) * 128;
  const int Gpad = cdiv(G, 128) * 128;

  char* base = (char*)d_ws;
  size_t used = 0;
  auto alloc = [&](size_t bytes) -> void* {
    void* p = base + used;
    used += (bytes + 255) & ~(size_t)255;
    return p;
  };
  // three N-row plane pairs
  us* PaH = (us*)alloc((size_t)Npad * KP * 2); us* PaL = (us*)alloc((size_t)Npad * KP * 2);
  us* PbH = (us*)alloc((size_t)Npad * KP * 2); us* PbL = (us*)alloc((size_t)Npad * KP * 2);
  us* PcH = (us*)alloc((size_t)Npad * KP * 2); us* PcL = (us*)alloc((size_t)Npad * KP * 2);
  // three G-row plane pairs
  us* QaH = (us*)alloc((size_t)Gpad * KP * 2); us* QaL = (us*)alloc((size_t)Gpad * KP * 2);
  us* QbH = (us*)alloc((size_t)Gpad * KP * 2); us* QbL = (us*)alloc((size_t)Gpad * KP * 2);
  us* QcH = (us*)alloc((size_t)Gpad * KP * 2); us* QcL = (us*)alloc((size_t)Gpad * KP * 2);
  // small weights (plane pairs, 384 rows)
  auto wsm = [&](void){ return (us*)alloc((size_t)384 * KP * 2); };
  us *wlin1H=wsm(), *wlin1L=wsm(), *wgeuH=wsm(), *wgeuL=wsm(), *wge2H=wsm(), *wge2L=wsm();
  us *wgatH[4], *wgatL[4];
  for (int l = 0; l < 4; ++l){ wgatH[l]=wsm(); wgatL[l]=wsm(); }
  us *wmolSH=wsm(), *wmolSL=wsm(), *wmolDH=wsm(), *wmolDL=wsm();
  // packed GRU weights: 6 sets
  us* Wgru[6];
  for (int l = 0; l < 6; ++l) Wgru[l] = (us*)alloc((size_t)1228800 * 2);
  float* Tt  = (float*)alloc((size_t)18 * KP * 4);
  float* vp  = (float*)alloc((size_t)18 * KP * 4);
  float* rv  = (float*)alloc((size_t)N * 4);
  float* adv = (float*)alloc((size_t)N * 4);
  float* asx = (float*)alloc((size_t)N * 4);
  // CSR
  const int SBS = 512;
  int nblk = cdiv(N, SBS);
  int* hist = (int*)alloc((size_t)N * 4);
  int* cnt  = (int*)alloc((size_t)N * 4);
  int* off  = (int*)alloc((size_t)(N + 1) * 4);
  int* bsum = (int*)alloc((size_t)nblk * 4);
  int* lst  = (int*)alloc((size_t)E * 4);
  int* goff = (int*)alloc((size_t)(G + 1) * 4);

  auto cvt2 = [&](const float* src, int ld, int M, us* hb, us* lb, int Mpad){
    int tot = Mpad * 80;
    k_cvt2<<<cdiv(tot, 256), 256, 0, stream>>>(src, ld, M, hb, lb, tot);
  };
  auto mm_p = [&](const us* ah, const us* al, const us* bh, const us* bl,
                  const float* bias, us* ch, us* cl, int M, int NC, int mode){
    int nwg = cdiv(M, 128) * 3;
    if (mode == 0)      k_mfma3<0><<<nwg, 256, 0, stream>>>(ah, al, bh, bl, bias, ch, cl, M, NC);
    else if (mode == 1) k_mfma3<1><<<nwg, 256, 0, stream>>>(ah, al, bh, bl, bias, ch, cl, M, NC);
    else                k_mfma3<2><<<nwg, 256, 0, stream>>>(ah, al, bh, bl, bias, ch, cl, M, NC);
  };
  auto gru = [&](const us* Ih, const us* Il, const us* Hh, const us* Hl,
                 const us* Wp, const float* bi, const float* bh,
                 us* Oh, us* Ol, int Mpad){
    int nwg = (Mpad / 128) * 10;
    k_gru<<<nwg, 256, 0, stream>>>(Ih, Il, Hh, Hl, Wp, bi, bh, Oh, Ol);
  };

  // ---- CSR build ----
  hipMemsetAsync(hist, 0, (size_t)N * 4, stream);
  k_hist<<<cdiv(E, 256), 256, 0, stream>>>(ei, E, hist);
  k_scanA<SBS><<<nblk, SBS, 0, stream>>>(hist, off, bsum, N);
  k_scanB<SBS><<<1, SBS, 0, stream>>>(bsum, nblk);
  k_scanC<SBS><<<nblk, SBS, 0, stream>>>(off, bsum, N);
  k_setN<<<1, 1, 0, stream>>>(off, N, E);
  hipMemsetAsync(cnt, 0, (size_t)N * 4, stream);
  k_fill<<<cdiv(E, 256), 256, 0, stream>>>(ei, E, off, cnt, lst);
  k_goff<<<cdiv(G + 1, 256), 256, 0, stream>>>(batch, N, G, goff);

  // ---- weights -> planes / packs / padded vectors ----
  cvt2(lin1_W, D, D, wlin1H, wlin1L, 384);
  cvt2(ge_lin1_W, 2 * D, D, wgeuH, wgeuL, 384);
  cvt2(ge_lin2_W, D, D, wge2H, wge2L, 384);
  for (int l = 0; l < 4; ++l) cvt2(gat_W + (size_t)l * D * D, D, D, wgatH[l], wgatL[l], 384);
  cvt2(mol_Ws, D, D, wmolSH, wmolSL, 384);
  cvt2(mol_Wd, D, D, wmolDH, wmolDL, 384);
  for (int l = 0; l < 5; ++l)
    k_wpack<<<1200, 256, 0, stream>>>(gru_wih + (size_t)l * 270000,
                                      gru_whh + (size_t)l * 270000, Wgru[l]);
  k_wpack<<<1200, 256, 0, stream>>>(mgru_wih, mgru_whh, Wgru[5]);
  k_table<<<18, 256, 0, stream>>>(ge_e1, ge_e2, ge_lin1_W, Tt);
  k_pads<<<cdiv(18 * KP, 256), 256, 0, stream>>>(ge_att_l, ge_att_r, gat_att_s, gat_att_d,
                                                 mol_att_s, mol_att_d, gat_b, mol_b, lin2_W, vp);

  // ---- init features ----
  k_embed2<<<cdiv(Npad * KP, 256), 256, 0, stream>>>(x, emb_atom, emb_chir, PaH, PaL, N, Npad * KP);
  mm_p(PaH, PaL, wlin1H, wlin1L, lin1_b, PbH, PbL, N, D, 1);       // xf -> Pb

  // ---- GATEConv ----
  mm_p(PbH, PbL, wgeuH, wgeuL, nullptr, PaH, PaL, N, D, 0);        // u -> Pa
  k_dot2<<<cdiv(N, 4), 256, 0, stream>>>(PbH, PbL, vp + 1 * KP, rv, N);
  k_gate_fused<<<cdiv(N, 4), 256, 0, stream>>>(PaH, PaL, Tt, vp, rv,
                                               ei, ea, off, lst, PcH, PcL, N);
  mm_p(PcH, PcL, wge2H, wge2L, ge_bias, PaH, PaL, N, D, 2);        // elu(h) -> Pa
  gru(PaH, PaL, PbH, PbL, Wgru[0], gru_bih, gru_bhh, PcH, PcL, Npad);   // xf -> Pc

  us *xfH = PcH, *xfL = PcL, *aH = PaH, *aL = PaL, *bH = PbH, *bL = PbL;
  // ---- GATConv layers 1..4 ----
  for (int l = 0; l < 4; ++l){
    mm_p(xfH, xfL, wgatH[l], wgatL[l], nullptr, aH, aL, N, D, 0);  // xw -> a
    k_dot2<<<cdiv(N, 4), 256, 0, stream>>>(aH, aL, vp + (2 + l) * KP, rv, N);
    k_dot2<<<cdiv(N, 4), 256, 0, stream>>>(aH, aL, vp + (6 + l) * KP, adv, N);
    k_gat_fused<<<cdiv(N, 4), 256, 0, stream>>>(aH, aL, rv, adv, ei, off, lst,
                                                vp + (12 + l) * KP, bH, bL, N);
    gru(bH, bL, xfH, xfL, Wgru[l + 1],
        gru_bih + (l + 1) * 900, gru_bhh + (l + 1) * 900, aH, aL, Npad);  // xf' -> a
    us* th = xfH; us* tl = xfL;
    xfH = aH; xfL = aL; aH = th; aL = tl;
  }

  // ---- attentive readout ----
  k_gsum<<<cdiv(G, 4), 256, 0, stream>>>(xfH, xfL, goff, QaH, QaL, G);      // OUT -> Qa
  mm_p(xfH, xfL, wmolSH, wmolSL, nullptr, aH, aL, N, D, 0);                 // xs -> a (pinned)
  k_dot2<<<cdiv(N, 4), 256, 0, stream>>>(aH, aL, vp + 10 * KP, asx, N);
  us *outH = QaH, *outL = QaL, *sgH = QbH, *sgL = QbL, *xdH = QcH, *xdL = QcL;
  for (int t = 0; t < 3; ++t){
    mm_p(outH, outL, wmolDH, wmolDL, nullptr, xdH, xdL, G, D, 0);           // xd
    k_dot2<<<cdiv(G, 4), 256, 0, stream>>>(xdH, xdL, vp + 11 * KP, adv, G);
    k_mol_fused<<<cdiv(G, 4), 256, 0, stream>>>(aH, aL, asx, adv, goff,
                                                vp + 16 * KP, sgH, sgL, G);
    gru(sgH, sgL, outH, outL, Wgru[5], mgru_bih, mgru_bhh, xdH, xdL, Gpad); // out' -> xd
    us* th = outH; us* tl = outL;
    outH = xdH; outL = xdL; xdH = th; xdL = tl;
  }
  k_final2<<<cdiv(G, 4), 256, 0, stream>>>(outH, outL, vp + 17 * KP, lin2_b, (float*)d_out, G);
}